// Round 2
// baseline (1839.867 us; speedup 1.0000x reference)
//
#include <hip/hip_runtime.h>
#include <stdint.h>

#define Tdim 128
#define Bdim 32
#define Sdim 64
#define Fdim 256

typedef unsigned short u16;
typedef short bf16x8 __attribute__((ext_vector_type(8)));
typedef float f32x4 __attribute__((ext_vector_type(4)));

#define K2     2.8853900817779268f   /* 2*log2(e) */
#define LOG2E  1.4426950408889634f

__device__ __forceinline__ u16 f2b(float f){
  union { float f; uint32_t u; } v; v.f = f;
  uint32_t u = v.u;
  if ((u & 0x7fffffffu) > 0x7f800000u) return (u16)0x7fc0;
  uint32_t r = (u + 0x7fffu + ((u >> 16) & 1u)) >> 16;
  return (u16)r;
}
__device__ __forceinline__ float b2f(u16 h){
  union { uint32_t u; float f; } v; v.u = ((uint32_t)h) << 16; return v.f;
}
__device__ __forceinline__ float b2f_lo(uint32_t w){
  union { uint32_t u; float f; } v; v.u = w << 16; return v.f;
}
__device__ __forceinline__ float b2f_hi(uint32_t w){
  union { uint32_t u; float f; } v; v.u = w & 0xffff0000u; return v.f;
}
__device__ __forceinline__ uint32_t pack2(float a, float b){
  return (uint32_t)f2b(a) | ((uint32_t)f2b(b) << 16);
}
__device__ __forceinline__ uint4 pack8(const float4 a, const float4 b){
  uint4 r;
  r.x = pack2(a.x, a.y); r.y = pack2(a.z, a.w);
  r.z = pack2(b.x, b.y); r.w = pack2(b.z, b.w);
  return r;
}

// Raw workgroup barrier WITHOUT the vmcnt(0) drain __syncthreads forces.
// LDS producer->consumer ordering: lgkmcnt(0) before s_barrier guarantees this
// wave's ds_writes (and ds_reads, for WAR) retired; the barrier makes it
// global across waves. Global loads to registers keep their own counted
// vmcnt waits at first use (compiler dependence tracking) and are NOT drained.
__device__ __forceinline__ void bar_lds(){
  asm volatile("s_waitcnt lgkmcnt(0)" ::: "memory");
  __builtin_amdgcn_s_barrier();
  asm volatile("" ::: "memory");
}

// ===========================================================================
// FAST PATH (requires ~136 MB workspace)
// ===========================================================================

// ---- Kernel 0: Wt[g][f] = bf16(W[f][g])  (fp32 -> bf16 transpose, 256x256)
__global__ __launch_bounds__(256) void kt_transpose_cvt(const float* __restrict__ Wg,
                                                        u16* __restrict__ Wt){
  __shared__ u16 tile[64*66];
  int bx = blockIdx.x;            // 16 blocks: 4x4 tiles of 64x64
  int ti = bx >> 2, tj = bx & 3;
  int t = threadIdx.x;
#pragma unroll
  for (int i = 0; i < 16; ++i){
    int e = t*16 + i;
    int r = e >> 6, c = e & 63;
    tile[r*66 + c] = f2b(Wg[(ti*64 + r)*256 + tj*64 + c]);
  }
  __syncthreads();
#pragma unroll
  for (int i = 0; i < 16; ++i){
    int e = t*16 + i;
    int r = e >> 6, c = e & 63;   // r = g-local, c = f-local
    Wt[(tj*64 + r)*256 + ti*64 + c] = tile[c*66 + r];
  }
}

// ---- Kernel 1: P = x@W via MFMA, stored as P[bt][grp][s][j] bf16 (grp=g>>4),
//      plus q[row] = x[row]·W_l (nt==0 blocks) and r[row] = x[row]·W_lc
//      (nt==1 blocks). grid 4096 = 2048 r-tiles x 2 g-tiles, 256 thr.
__global__ __launch_bounds__(256) void kt_gemm(const float* __restrict__ Xg,
                                               const u16* __restrict__ Wt,
                                               const float* __restrict__ Wlg,
                                               const float* __restrict__ Wlcg,
                                               u16* __restrict__ Pg,
                                               float* __restrict__ qg,
                                               float* __restrict__ rg){
  __shared__ u16 Ws[128*72];   // [g-local][k-local] pad 64->72
  __shared__ u16 Xs[128*72];   // [r-local][k-local]
  __shared__ float Wls[256];
  int t  = threadIdx.x;
  int bx = blockIdx.x;
  int mt = bx >> 1, nt = bx & 1;
  int r0 = mt*128, g0 = nt*128;
  Wls[t & 255] = (nt == 0) ? Wlg[t & 255] : Wlcg[t & 255];
  int lane = t & 63, wv = t >> 6;
  int goff = (wv & 1)*64, roff = (wv >> 1)*64;
  int fr = lane & 15, fq = lane >> 4;
  f32x4 acc[4][4];
#pragma unroll
  for (int a = 0; a < 4; ++a)
#pragma unroll
    for (int b = 0; b < 4; ++b)
      acc[a][b] = (f32x4){0.f,0.f,0.f,0.f};
  float qacc = 0.f;

  for (int kk = 0; kk < 4; ++kk){
    int k0 = kk*64;
    __syncthreads();   // protect LDS reuse from previous iteration
#pragma unroll
    for (int uu = 0; uu < 4; ++uu){
      int unit = uu*256 + t;          // 0..1023
      int row = unit >> 3, c = unit & 7;
      // W tile: already bf16
      *(uint4*)&Ws[row*72 + c*8] = *(const uint4*)&Wt[(g0+row)*256 + k0 + c*8];
      // x tile: fp32 -> bf16 convert
      const float4* xp = (const float4*)&Xg[(size_t)(r0+row)*256 + k0 + c*8];
      *(uint4*)&Xs[row*72 + c*8] = pack8(xp[0], xp[1]);
    }
    __syncthreads();
    if (t < 128){
      int r = t;
#pragma unroll
      for (int c = 0; c < 8; ++c){
        uint4 xv = *(const uint4*)&Xs[r*72 + c*8];
        const uint32_t* xw = (const uint32_t*)&xv;
#pragma unroll
        for (int p = 0; p < 4; ++p){
          qacc = fmaf(b2f_lo(xw[p]), Wls[k0 + c*8 + 2*p],     qacc);
          qacc = fmaf(b2f_hi(xw[p]), Wls[k0 + c*8 + 2*p + 1], qacc);
        }
      }
    }
#pragma unroll
    for (int ks = 0; ks < 64; ks += 32){
      bf16x8 af[4], bf_[4];
#pragma unroll
      for (int mi = 0; mi < 4; ++mi)
        af[mi] = *(const bf16x8*)&Ws[(goff + mi*16 + fr)*72 + ks + fq*8];
#pragma unroll
      for (int ni = 0; ni < 4; ++ni)
        bf_[ni] = *(const bf16x8*)&Xs[(roff + ni*16 + fr)*72 + ks + fq*8];
#pragma unroll
      for (int mi = 0; mi < 4; ++mi)
#pragma unroll
        for (int ni = 0; ni < 4; ++ni)
          acc[mi][ni] = __builtin_amdgcn_mfma_f32_16x16x32_bf16(
              af[mi], bf_[ni], acc[mi][ni], 0, 0, 0);
    }
  }
  // epilogue: D row m -> g = g0+goff+mi*16+fq*4+reg ; D col n -> r
#pragma unroll
  for (int mi = 0; mi < 4; ++mi){
    int g = g0 + goff + mi*16 + fq*4;
    int grp = g >> 4;                 // j0 = fq*4 = g & 15
#pragma unroll
    for (int ni = 0; ni < 4; ++ni){
      int r = r0 + roff + ni*16 + fr;
      int bt = r >> 6, s = r & 63;
      ushort4 st;
      st.x = f2b(acc[mi][ni][0]); st.y = f2b(acc[mi][ni][1]);
      st.z = f2b(acc[mi][ni][2]); st.w = f2b(acc[mi][ni][3]);
      *(ushort4*)&Pg[(size_t)bt*16384 + grp*1024 + s*16 + fq*4] = st;
    }
  }
  if (t < 128){
    if (nt == 0) qg[r0 + t] = qacc;
    else if (rg) rg[r0 + t] = qacc;
  }
}

// ---- Kernel 2 (v4): sequential scan, raw barriers (no vmcnt drains),
//      fully wave-replicated gate via precomputed r = x·Wlc.
//  A: GEMV c=ctx@Wc (shfl-reduced)                      -> bar
//  B: fused tanh + ait partials -> pp                   -> bar
//  C: replicated softmax; glc += Σ a_s r_s (shfl);
//     gate(t+1) in regs; attended partials -> attp      -> bar
//  D: reduce attp -> att; ctx update; outO/outC         -> bar
__global__ __launch_bounds__(1024) void kt_scan4(
    const float* __restrict__ Xg, const u16* __restrict__ Pf,
    const float* __restrict__ qf, const float* __restrict__ rf,
    const float* __restrict__ Wcg, const float* __restrict__ blg,
    const float* __restrict__ biasg, const float* __restrict__ ug,
    float* __restrict__ out)
{
  __shared__ float ctx_s[256], c_s[256], bbr_s[256], ur_s[256];
  __shared__ float pp[64*17];        // ait partials [s][grp], stride 17
  __shared__ float attp[16*260];     // attended partials [wave][f]

  const int tid   = threadIdx.x;
  const int b     = blockIdx.x;
  const int lane  = tid & 63;
  const int wave  = tid >> 6;          // 0..15
  const int g_loc = lane >> 2;         // GEMV: g-local 0..15
  const int fc    = lane & 3;          // GEMV: f-chunk (64 f each)
  const int gcol  = wave*16 + g_loc;   // GEMV output column
  const int f     = tid & 255;         // D-phase f-ownership

  // one-time: Wc slice in regs, bf16-packed, PRE-ROTATED by fc (bank-friendly)
  uint32_t wcp2[32];
#pragma unroll
  for (int i = 0; i < 16; ++i){
    int m  = (4*fc + i) & 15;
    int fb = fc*64 + m*4;
    wcp2[2*i]   = pack2(Wcg[(fb+0)*256 + gcol], Wcg[(fb+1)*256 + gcol]);
    wcp2[2*i+1] = pack2(Wcg[(fb+2)*256 + gcol], Wcg[(fb+3)*256 + gcol]);
  }

  if (tid < 256){
    ctx_s[tid] = 0.f;
    bbr_s[tid] = K2 * biasg[tid];
    ur_s[tid]  = ug[tid];
  }
  const float blf = blg[0];
  float glcr = 0.f;                    // replicated in every wave

  // per-thread streaming pointers
  const u16*    pP = Pf + (size_t)(b*Tdim)*16384 + wave*1024 + lane*16;
  const float4* pX = (const float4*)Xg + (size_t)(b*Tdim)*4096 + wave*256 + lane;
  const float*  pq = qf + (size_t)(b*Tdim)*64 + lane;
  const float*  pr = rf + (size_t)(b*Tdim)*64 + lane;

  // preamble: P(0) to regs, r(0), gate(0) (glc(0)=0)
  uint32_t pw[8];
  {
    const uint4* pp_ = (const uint4*)pP;
    *(uint4*)&pw[0] = pp_[0]; *(uint4*)&pw[4] = pp_[1];
  }
  float rcur = pr[0];
  float l2r, l2br;
  {
    float logit = blf + pq[0];
    float sig = __builtin_amdgcn_rcpf(1.f + __builtin_exp2f(-LOG2E*logit));
    l2r  = K2 * sig;
    l2br = K2 - K2*sig;
  }

  float* outO = out;
  float* outC = out + Bdim*Tdim*Fdim;
  float* outW = out + 2*Bdim*Tdim*Fdim;
  __syncthreads();   // one full barrier: LDS consts + preamble visible

  for (int tt = 0; tt < Tdim; ++tt){
    const int bt    = b*Tdim + tt;
    const int nstep = (tt < Tdim-1) ? 1 : 0;

    // ---- prefetch issues (drain at first USE, not at barriers) ----
    uint32_t pwn[8];                               // P(t+1): used in B(t+1)
    {
      const uint4* pp_ = (const uint4*)(pP + (size_t)nstep*16384);
      *(uint4*)&pwn[0] = pp_[0]; *(uint4*)&pwn[4] = pp_[4/4];
    }
    float4 x0 = pX[0], x1 = pX[64], x2 = pX[128], x3 = pX[192];  // x(t): used in C(t)
    float qn = pq[nstep*64];                       // q(t+1): used in C(t)
    float rn = pr[nstep*64];                       // r(t+1): used in C(t+1)

    // ================= A: GEMV c = ctx@Wc =================
    {
      float pa = 0.f;
#pragma unroll
      for (int i = 0; i < 16; ++i){
        int m = (4*fc + i) & 15;               // rotated f-subblock
        float4 cv = *(const float4*)&ctx_s[fc*64 + m*4];
        pa = fmaf(cv.x, b2f_lo(wcp2[2*i]),   pa);
        pa = fmaf(cv.y, b2f_hi(wcp2[2*i]),   pa);
        pa = fmaf(cv.z, b2f_lo(wcp2[2*i+1]), pa);
        pa = fmaf(cv.w, b2f_hi(wcp2[2*i+1]), pa);
      }
      pa += __shfl_xor(pa, 1, 64);
      pa += __shfl_xor(pa, 2, 64);
      if (fc == 0) c_s[gcol] = pa;
    }
    bar_lds();                                     // B1: c_s visible

    // ================= B: fused tanh + ait partials =================
    {
      const float l2  = l2r;
      const float l2b = l2br;
      const float4* cs4 = (const float4*)&c_s[wave*16];
      const float4* bb4 = (const float4*)&bbr_s[wave*16];
      const float4* uu4 = (const float4*)&ur_s[wave*16];
      float ait = 0.f;
#pragma unroll
      for (int k = 0; k < 4; ++k){
        float4 cq = cs4[k], bq = bb4[k], uq = uu4[k];
        uint32_t wa = pw[2*k], wb = pw[2*k+1];
        float z, e, r;
        z = fmaf(l2, b2f_lo(wa), fmaf(l2b, cq.x, bq.x));
        e = __builtin_exp2f(z); r = __builtin_amdgcn_rcpf(e + 1.f);
        ait += fmaf(-2.f*uq.x, r, uq.x);
        z = fmaf(l2, b2f_hi(wa), fmaf(l2b, cq.y, bq.y));
        e = __builtin_exp2f(z); r = __builtin_amdgcn_rcpf(e + 1.f);
        ait += fmaf(-2.f*uq.y, r, uq.y);
        z = fmaf(l2, b2f_lo(wb), fmaf(l2b, cq.z, bq.z));
        e = __builtin_exp2f(z); r = __builtin_amdgcn_rcpf(e + 1.f);
        ait += fmaf(-2.f*uq.z, r, uq.z);
        z = fmaf(l2, b2f_hi(wb), fmaf(l2b, cq.w, bq.w));
        e = __builtin_exp2f(z); r = __builtin_amdgcn_rcpf(e + 1.f);
        ait += fmaf(-2.f*uq.w, r, uq.w);
      }
      pp[lane*17 + wave] = ait;
    }
    bar_lds();                                     // B2: pp visible

    // ================= C: softmax + glc/gate + attended =================
    {
      const int ppb = lane*17;
      float ait = 0.f;
#pragma unroll
      for (int k = 0; k < 16; ++k) ait += pp[ppb + k];
      float mx = ait;
#pragma unroll
      for (int off = 32; off > 0; off >>= 1)
        mx = fmaxf(mx, __shfl_xor(mx, off, 64));
      float e = __builtin_exp2f(LOG2E*(ait - mx));
      float ssum = e;
#pragma unroll
      for (int off = 32; off > 0; off >>= 1)
        ssum += __shfl_xor(ssum, off, 64);
      float denom = ssum + 1e-7f * __builtin_exp2f(-LOG2E*mx);
      float a = e * __builtin_amdgcn_rcpf(denom);
      if (wave == 0) outW[(size_t)bt*Sdim + lane] = a;

      // glc increment + gate(t+1), replicated per wave, all in regs
      float ga = a * rcur;
#pragma unroll
      for (int off = 32; off > 0; off >>= 1)
        ga += __shfl_xor(ga, off, 64);
      glcr += ga;
      {
        float logit = glcr + blf + qn;
        float sig = __builtin_amdgcn_rcpf(1.f + __builtin_exp2f(-LOG2E*logit));
        l2r  = K2 * sig;
        l2br = K2 - K2*sig;
      }

      // attended partials: this thread owns s in [4w,4w+4), f in [4l,4l+4)
      const float av0 = __shfl(a, wave*4 + 0, 64);
      const float av1 = __shfl(a, wave*4 + 1, 64);
      const float av2 = __shfl(a, wave*4 + 2, 64);
      const float av3 = __shfl(a, wave*4 + 3, 64);
      float4 acc;
      acc.x = av0*x0.x; acc.y = av0*x0.y; acc.z = av0*x0.z; acc.w = av0*x0.w;
      acc.x = fmaf(av1, x1.x, acc.x); acc.y = fmaf(av1, x1.y, acc.y);
      acc.z = fmaf(av1, x1.z, acc.z); acc.w = fmaf(av1, x1.w, acc.w);
      acc.x = fmaf(av2, x2.x, acc.x); acc.y = fmaf(av2, x2.y, acc.y);
      acc.z = fmaf(av2, x2.z, acc.z); acc.w = fmaf(av2, x2.w, acc.w);
      acc.x = fmaf(av3, x3.x, acc.x); acc.y = fmaf(av3, x3.y, acc.y);
      acc.z = fmaf(av3, x3.z, acc.z); acc.w = fmaf(av3, x3.w, acc.w);
      *(float4*)&attp[wave*260 + lane*4] = acc;
    }
    bar_lds();                                     // B3: attp visible

    // ================= D: reduce + ctx update + outputs =================
    if (tid < 256){
      float att = 0.f;
#pragma unroll
      for (int k = 0; k < 16; ++k) att += attp[k*260 + f];
      const size_t o = (size_t)bt*Fdim + f;
      outO[o] = att;
      float nc = ctx_s[f] + att;
      ctx_s[f] = nc;
      outC[o] = nc;
    }
    bar_lds();                                     // B4: ctx_s visible for A(t+1)

    // rotate prefetched state
#pragma unroll
    for (int k = 0; k < 8; ++k) pw[k] = pwn[k];
    rcur = rn;
    pP += (size_t)nstep*16384;
    pX += 4096;
    pq += 64;
    pr += 64;
  }
}

// ---- Kernel 2 (v3): kept as tier-1 fallback (workspace without r buffer).
__global__ __launch_bounds__(1024) void kt_scan3(
    const float* __restrict__ Xg, const u16* __restrict__ Pf,
    const float* __restrict__ qf, const float* __restrict__ Wcg,
    const float* __restrict__ Wlcg, const float* __restrict__ blg,
    const float* __restrict__ biasg, const float* __restrict__ ug,
    float* __restrict__ out)
{
  __shared__ float ctx_s[256], c_s[256], wlc_s[256], bbr_s[256], ur_s[256];
  __shared__ float pp[64*17];
  __shared__ float attp[16*260];
  __shared__ float l2_s[64], l2b_s[64];
  __shared__ float glc_p[4];

  const int tid   = threadIdx.x;
  const int b     = blockIdx.x;
  const int lane  = tid & 63;
  const int wave  = tid >> 6;
  const int g_loc = lane >> 2;
  const int fc    = lane & 3;
  const int gcol  = wave*16 + g_loc;
  const int f     = tid & 255;

  uint32_t wcp2[32];
#pragma unroll
  for (int i = 0; i < 16; ++i){
    int m  = (4*fc + i) & 15;
    int fb = fc*64 + m*4;
    wcp2[2*i]   = pack2(Wcg[(fb+0)*256 + gcol], Wcg[(fb+1)*256 + gcol]);
    wcp2[2*i+1] = pack2(Wcg[(fb+2)*256 + gcol], Wcg[(fb+3)*256 + gcol]);
  }

  if (tid < 256){
    ctx_s[tid] = 0.f;
    wlc_s[tid] = Wlcg[tid];
    bbr_s[tid] = K2 * biasg[tid];
    ur_s[tid]  = ug[tid];
  }
  if (tid < 4) glc_p[tid] = 0.f;
  const float blf = blg[0];
  float glcr = 0.f;
  float qcur = 0.f, qnxt = 0.f;
  if (wave == 0) qcur = qf[(size_t)(b*Tdim)*64 + lane];

  float* outO = out;
  float* outC = out + Bdim*Tdim*Fdim;
  float* outW = out + 2*Bdim*Tdim*Fdim;
  __syncthreads();

  for (int tt = 0; tt < Tdim; ++tt){
    const int bt  = b*Tdim + tt;
    const int btn = (tt < Tdim-1) ? bt+1 : bt;

    uint32_t pw[8];
    {
      const uint4* pp_ = (const uint4*)&Pf[(size_t)bt*16384 + wave*1024 + lane*16];
      *(uint4*)&pw[0] = pp_[0];
      *(uint4*)&pw[4] = pp_[1];
    }
    if (wave == 0) qnxt = qf[(size_t)btn*64 + lane];

    {
      float pa = 0.f;
#pragma unroll
      for (int i = 0; i < 16; ++i){
        int m = (4*fc + i) & 15;
        float4 cv = *(const float4*)&ctx_s[fc*64 + m*4];
        pa = fmaf(cv.x, b2f_lo(wcp2[2*i]),   pa);
        pa = fmaf(cv.y, b2f_hi(wcp2[2*i]),   pa);
        pa = fmaf(cv.z, b2f_lo(wcp2[2*i+1]), pa);
        pa = fmaf(cv.w, b2f_hi(wcp2[2*i+1]), pa);
      }
      pa += __shfl_xor(pa, 1, 64);
      pa += __shfl_xor(pa, 2, 64);
      if (fc == 0) c_s[gcol] = pa;
    }

    if (wave == 0){
      glcr += glc_p[0] + glc_p[1] + glc_p[2] + glc_p[3];
      float logit = glcr + blf + qcur;
      float sig = __builtin_amdgcn_rcpf(1.f + __builtin_exp2f(-LOG2E*logit));
      l2_s[lane]  = K2 * sig;
      l2b_s[lane] = K2 - K2*sig;
    }
    __syncthreads();

    float4 x0, x1, x2, x3;
    {
      const float4* xP = (const float4*)Xg + (size_t)bt*4096 + wave*256 + lane;
      x0 = xP[0]; x1 = xP[64]; x2 = xP[128]; x3 = xP[192];
    }
    {
      const float l2  = l2_s[lane];
      const float l2b = l2b_s[lane];
      const float4* cs4 = (const float4*)&c_s[wave*16];
      const float4* bb4 = (const float4*)&bbr_s[wave*16];
      const float4* uu4 = (const float4*)&ur_s[wave*16];
      float ait = 0.f;
#pragma unroll
      for (int k = 0; k < 4; ++k){
        float4 cq = cs4[k], bq = bb4[k], uq = uu4[k];
        uint32_t wa = pw[2*k], wb = pw[2*k+1];
        float z, e, r;
        z = fmaf(l2, b2f_lo(wa), fmaf(l2b, cq.x, bq.x));
        e = __builtin_exp2f(z); r = __builtin_amdgcn_rcpf(e + 1.f);
        ait += fmaf(-2.f*uq.x, r, uq.x);
        z = fmaf(l2, b2f_hi(wa), fmaf(l2b, cq.y, bq.y));
        e = __builtin_exp2f(z); r = __builtin_amdgcn_rcpf(e + 1.f);
        ait += fmaf(-2.f*uq.y, r, uq.y);
        z = fmaf(l2, b2f_lo(wb), fmaf(l2b, cq.z, bq.z));
        e = __builtin_exp2f(z); r = __builtin_amdgcn_rcpf(e + 1.f);
        ait += fmaf(-2.f*uq.z, r, uq.z);
        z = fmaf(l2, b2f_hi(wb), fmaf(l2b, cq.w, bq.w));
        e = __builtin_exp2f(z); r = __builtin_amdgcn_rcpf(e + 1.f);
        ait += fmaf(-2.f*uq.w, r, uq.w);
      }
      pp[lane*17 + wave] = ait;
    }
    __syncthreads();

    {
      const int ppb = lane*17;
      float ait = 0.f;
#pragma unroll
      for (int k = 0; k < 16; ++k) ait += pp[ppb + k];
      float mx = ait;
#pragma unroll
      for (int off = 32; off > 0; off >>= 1)
        mx = fmaxf(mx, __shfl_xor(mx, off, 64));
      float e = __builtin_exp2f(LOG2E*(ait - mx));
      float ssum = e;
#pragma unroll
      for (int off = 32; off > 0; off >>= 1)
        ssum += __shfl_xor(ssum, off, 64);
      float denom = ssum + 1e-7f * __builtin_exp2f(-LOG2E*mx);
      float a = e * __builtin_amdgcn_rcpf(denom);
      if (wave == 0) outW[(size_t)bt*Sdim + lane] = a;

      const float av0 = __shfl(a, wave*4 + 0, 64);
      const float av1 = __shfl(a, wave*4 + 1, 64);
      const float av2 = __shfl(a, wave*4 + 2, 64);
      const float av3 = __shfl(a, wave*4 + 3, 64);
      float4 acc;
      acc.x = av0*x0.x; acc.y = av0*x0.y; acc.z = av0*x0.z; acc.w = av0*x0.w;
      acc.x = fmaf(av1, x1.x, acc.x); acc.y = fmaf(av1, x1.y, acc.y);
      acc.z = fmaf(av1, x1.z, acc.z); acc.w = fmaf(av1, x1.w, acc.w);
      acc.x = fmaf(av2, x2.x, acc.x); acc.y = fmaf(av2, x2.y, acc.y);
      acc.z = fmaf(av2, x2.z, acc.z); acc.w = fmaf(av2, x2.w, acc.w);
      acc.x = fmaf(av3, x3.x, acc.x); acc.y = fmaf(av3, x3.y, acc.y);
      acc.z = fmaf(av3, x3.z, acc.z); acc.w = fmaf(av3, x3.w, acc.w);
      *(float4*)&attp[wave*260 + lane*4] = acc;
    }
    __syncthreads();

    if (tid < 256){
      float att = 0.f;
#pragma unroll
      for (int k = 0; k < 16; ++k) att += attp[k*260 + f];
      const size_t o = (size_t)bt*Fdim + f;
      outO[o] = att;
      float nc = ctx_s[f] + att;
      ctx_s[f] = nc;
      outC[o] = nc;
      float gp = att * wlc_s[f];
#pragma unroll
      for (int off = 32; off > 0; off >>= 1)
        gp += __shfl_xor(gp, off, 64);
      if (lane == 0) glc_p[wave] = gp;
    }
    qcur = qnxt;
    __syncthreads();
  }
}

// ===========================================================================
// FALLBACK (zero workspace) — the round-3 passing kernel, verbatim.
// ===========================================================================
__global__ __launch_bounds__(1024) void fused_ctx_attn(
    const float* __restrict__ Xg, const float* __restrict__ Wg,
    const float* __restrict__ Wcg, const float* __restrict__ Wlg,
    const float* __restrict__ Wlcg, const float* __restrict__ blg,
    const float* __restrict__ biasg, const float* __restrict__ ug,
    float* __restrict__ out)
{
  __shared__ u16   xs[64*272];
  __shared__ float ps[64*257];
  __shared__ float cpart[8*258];
  __shared__ float qp[64*5];
  __shared__ float pp[64*17];
  __shared__ float attp[4*260];
  __shared__ float ctx_s[256], c_s[256], bb_s[256], u_s[256], wlc_s[256], wl_s[256];
  __shared__ float l2_s[64], l2b_s[64], a_s[64];
  __shared__ float glc_p[4];

  const int tid  = threadIdx.x;
  const int b    = blockIdx.x;
  const int lane = tid & 63;
  const int wave = tid >> 6;
  const int fr   = lane & 15;
  const int fq   = lane >> 4;
  const int f    = tid & 255;
  const int sb   = tid >> 8;

  bf16x8 afW[8];
  {
    const int gcol = wave*16 + fr;
#pragma unroll
    for (int kt = 0; kt < 8; ++kt){
      u16 tmp[8];
#pragma unroll
      for (int j = 0; j < 8; ++j)
        tmp[j] = f2b(Wg[(kt*32 + fq*8 + j)*256 + gcol]);
      afW[kt] = *(const bf16x8*)tmp;
    }
  }
  const int fj = tid >> 7;
  const int gp = tid & 127;
  uint32_t wcp[32];
#pragma unroll
  for (int fi = 0; fi < 32; ++fi)
    wcp[fi] = pack2(Wcg[(fj*32 + fi)*256 + gp*2], Wcg[(fj*32 + fi)*256 + gp*2 + 1]);

  if (tid < 256){
    ctx_s[tid] = 0.f;
    bb_s[tid]  = K2 * biasg[tid];
    u_s[tid]   = ug[tid];
    wlc_s[tid] = Wlcg[tid];
    wl_s[tid]  = Wlg[tid];
  }
  if (tid < 4) glc_p[tid] = 0.f;
  const float blf = blg[0];
  float glcr = 0.f;

  float* outO = out;
  float* outC = out + Bdim*Tdim*Fdim;
  float* outW = out + 2*Bdim*Tdim*Fdim;

  const int srow = tid >> 5;
  const int sc8  = (tid & 31)*8;
  {
    const long xb = (long)(b*Tdim)*Sdim*Fdim;
    const float4* p0 = (const float4*)&Xg[xb + (long)srow*256 + sc8];
    const float4* p1 = (const float4*)&Xg[xb + (long)(srow+32)*256 + sc8];
    *(uint4*)&xs[srow*272 + sc8]      = pack8(p0[0], p0[1]);
    *(uint4*)&xs[(srow+32)*272 + sc8] = pack8(p1[0], p1[1]);
  }
  __syncthreads();

  for (int tt = 0; tt < Tdim; ++tt){
    const int tn = (tt < Tdim-1) ? (tt+1) : tt;
    const long xb = (long)((b*Tdim + tn))*Sdim*Fdim;
    const float4* p0 = (const float4*)&Xg[xb + (long)srow*256 + sc8];
    const float4* p1 = (const float4*)&Xg[xb + (long)(srow+32)*256 + sc8];
    uint4 xr0 = pack8(p0[0], p0[1]);
    uint4 xr1 = pack8(p1[0], p1[1]);

    {
      float pa = 0.f, pb = 0.f;
#pragma unroll
      for (int fi = 0; fi < 32; ++fi){
        float cf = ctx_s[fj*32 + fi];
        pa = fmaf(cf, b2f_lo(wcp[fi]), pa);
        pb = fmaf(cf, b2f_hi(wcp[fi]), pb);
      }
      float2 st; st.x = pa; st.y = pb;
      *(float2*)&cpart[fj*258 + gp*2] = st;
    }
    {
      f32x4 acc[4];
#pragma unroll
      for (int nt = 0; nt < 4; ++nt) acc[nt] = (f32x4){0.f,0.f,0.f,0.f};
#pragma unroll
      for (int kt = 0; kt < 8; ++kt){
#pragma unroll
        for (int nt = 0; nt < 4; ++nt){
          bf16x8 bfx = *(const bf16x8*)&xs[(nt*16 + fr)*272 + kt*32 + fq*8];
          acc[nt] = __builtin_amdgcn_mfma_f32_16x16x32_bf16(afW[kt], bfx, acc[nt], 0, 0, 0);
        }
      }
#pragma unroll
      for (int nt = 0; nt < 4; ++nt){
        const int s = nt*16 + fr;
        const int g = wave*16 + fq*4;
        ps[s*257 + g + 0] = acc[nt][0];
        ps[s*257 + g + 1] = acc[nt][1];
        ps[s*257 + g + 2] = acc[nt][2];
        ps[s*257 + g + 3] = acc[nt][3];
      }
    }
    if (tid < 256){
      const int s = tid >> 2, qtr = tid & 3;
      float a = 0.f;
#pragma unroll
      for (int j = 0; j < 64; ++j)
        a = fmaf(b2f(xs[s*272 + qtr*64 + j]), wl_s[qtr*64 + j], a);
      qp[s*5 + qtr] = a;
    }
    __syncthreads();

    if (tid < 256){
      float a = 0.f;
#pragma unroll
      for (int k = 0; k < 8; ++k) a += cpart[k*258 + tid];
      c_s[tid] = a;
    }
    if (tid < 64){
      glcr += glc_p[0] + glc_p[1] + glc_p[2] + glc_p[3];
      float q = qp[tid*5] + qp[tid*5+1] + qp[tid*5+2] + qp[tid*5+3];
      float logit = glcr + blf + q;
      float sig = 1.f / (1.f + __builtin_exp2f(-LOG2E*logit));
      l2_s[tid]  = K2 * sig;
      l2b_s[tid] = K2 - K2*sig;
    }
    __syncthreads();

    {
      const float cf = c_s[f], bbf = bb_s[f], uf = u_s[f], n2 = -2.f*u_s[f];
#pragma unroll
      for (int i = 0; i < 16; ++i){
        const int s = sb*16 + i;
        float z2 = fmaf(l2_s[s], ps[s*257 + f], fmaf(l2b_s[s], cf, bbf));
        float e  = __builtin_exp2f(z2);
        float r  = 1.f / (e + 1.f);
        ps[s*257 + f] = fmaf(n2, r, uf);
      }
    }
    __syncthreads();

    {
      const int s = tid & 63, grp = tid >> 6;
      float a = 0.f;
#pragma unroll
      for (int k = 0; k < 16; ++k) a += ps[s*257 + grp*16 + k];
      pp[s*17 + grp] = a;
    }
    __syncthreads();

    if (tid < 64){
      const int s = tid;
      float ait = 0.f;
#pragma unroll
      for (int k = 0; k < 16; ++k) ait += pp[s*17 + k];
      float m = ait;
#pragma unroll
      for (int off = 32; off > 0; off >>= 1)
        m = fmaxf(m, __shfl_xor(m, off, 64));
      float e = __builtin_exp2f(LOG2E*(ait - m));
      float ssum = e;
#pragma unroll
      for (int off = 32; off > 0; off >>= 1)
        ssum += __shfl_xor(ssum, off, 64);
      float denom = ssum + 1e-7f * __builtin_exp2f(-LOG2E*m);
      float a = e / denom;
      a_s[s] = a;
      outW[(b*Tdim + tt)*Sdim + s] = a;
    }
    __syncthreads();

    {
      float ap = 0.f;
#pragma unroll
      for (int i = 0; i < 16; ++i){
        const int s = sb*16 + i;
        ap = fmaf(a_s[s], b2f(xs[s*272 + f]), ap);
      }
      attp[sb*260 + f] = ap;
    }
    __syncthreads();

    if (tid < 256){
      float att = attp[f] + attp[260+f] + attp[520+f] + attp[780+f];
      const int o = (b*Tdim + tt)*Fdim + f;
      outO[o] = att;
      float nc = ctx_s[f] + att;
      ctx_s[f] = nc;
      outC[o] = nc;
      float gpart = att * wlc_s[f];
#pragma unroll
      for (int off = 32; off > 0; off >>= 1)
        gpart += __shfl_xor(gpart, off, 64);
      if (lane == 0) glc_p[wave] = gpart;
    }
    *(uint4*)&xs[srow*272 + sc8] = xr0;
    *(uint4*)&xs[(srow+32)*272 + sc8] = xr1;
    __syncthreads();
  }
}

// ---------------------------------------------------------------------------
extern "C" void kernel_launch(void* const* d_in, const int* in_sizes, int n_in,
                              void* d_out, int out_size, void* d_ws, size_t ws_size,
                              hipStream_t stream){
  const float* x    = (const float*)d_in[0];
  const float* W    = (const float*)d_in[1];
  const float* Wc   = (const float*)d_in[2];
  const float* Wl   = (const float*)d_in[3];
  const float* Wlc  = (const float*)d_in[4];
  const float* bl   = (const float*)d_in[5];
  const float* bias = (const float*)d_in[6];
  const float* u    = (const float*)d_in[7];
  float* out = (float*)d_out;

  const size_t P_BYTES  = (size_t)4096*16384*2;   // 134217728
  const size_t Q_BYTES  = (size_t)262144*4;       // 1048576
  const size_t R_BYTES  = (size_t)262144*4;       // 1048576
  const size_t WT_BYTES = (size_t)256*256*2;      // 131072
  const size_t NEED1 = P_BYTES + Q_BYTES + WT_BYTES;
  const size_t NEED2 = P_BYTES + Q_BYTES + R_BYTES + WT_BYTES;

  if (ws_size >= NEED2){
    uint8_t* ws = (uint8_t*)d_ws;
    u16*   P  = (u16*)ws;
    float* q  = (float*)(ws + P_BYTES);
    float* r  = (float*)(ws + P_BYTES + Q_BYTES);
    u16*   Wt = (u16*)(ws + P_BYTES + Q_BYTES + R_BYTES);
    kt_transpose_cvt<<<16, 256, 0, stream>>>(W, Wt);
    kt_gemm<<<4096, 256, 0, stream>>>(x, Wt, Wl, Wlc, P, q, r);
    kt_scan4<<<Bdim, 1024, 0, stream>>>(x, P, q, r, Wc, bl, bias, u, out);
  } else if (ws_size >= NEED1){
    uint8_t* ws = (uint8_t*)d_ws;
    u16*   P  = (u16*)ws;
    float* q  = (float*)(ws + P_BYTES);
    u16*   Wt = (u16*)(ws + P_BYTES + Q_BYTES);
    kt_transpose_cvt<<<16, 256, 0, stream>>>(W, Wt);
    kt_gemm<<<4096, 256, 0, stream>>>(x, Wt, Wl, Wlc, P, q, nullptr);
    kt_scan3<<<Bdim, 1024, 0, stream>>>(x, P, q, Wc, Wlc, bl, bias, u, out);
  } else {
    fused_ctx_attn<<<Bdim, 1024, 0, stream>>>(x, W, Wc, Wl, Wlc, bl, bias, u, out);
  }
}

// Round 3
// 1081.992 us; speedup vs baseline: 1.7004x; 1.7004x over previous
//
#include <hip/hip_runtime.h>
#include <stdint.h>

#define Tdim 128
#define Bdim 32
#define Sdim 64
#define Fdim 256

typedef unsigned short u16;
typedef short bf16x8 __attribute__((ext_vector_type(8)));
typedef float f32x4 __attribute__((ext_vector_type(4)));

#define K2     2.8853900817779268f   /* 2*log2(e) */
#define LOG2E  1.4426950408889634f

__device__ __forceinline__ u16 f2b(float f){
  union { float f; uint32_t u; } v; v.f = f;
  uint32_t u = v.u;
  if ((u & 0x7fffffffu) > 0x7f800000u) return (u16)0x7fc0;
  uint32_t r = (u + 0x7fffu + ((u >> 16) & 1u)) >> 16;
  return (u16)r;
}
__device__ __forceinline__ float b2f(u16 h){
  union { uint32_t u; float f; } v; v.u = ((uint32_t)h) << 16; return v.f;
}
__device__ __forceinline__ float b2f_lo(uint32_t w){
  union { uint32_t u; float f; } v; v.u = w << 16; return v.f;
}
__device__ __forceinline__ float b2f_hi(uint32_t w){
  union { uint32_t u; float f; } v; v.u = w & 0xffff0000u; return v.f;
}
__device__ __forceinline__ uint32_t pack2(float a, float b){
  return (uint32_t)f2b(a) | ((uint32_t)f2b(b) << 16);
}
__device__ __forceinline__ uint4 pack8(const float4 a, const float4 b){
  uint4 r;
  r.x = pack2(a.x, a.y); r.y = pack2(a.z, a.w);
  r.z = pack2(b.x, b.y); r.w = pack2(b.z, b.w);
  return r;
}

// ===========================================================================
// FAST PATH (requires ~135 MB workspace)
// ===========================================================================

// ---- Kernel 0: Wt[g][f] = bf16(W[f][g])  (fp32 -> bf16 transpose, 256x256)
__global__ __launch_bounds__(256) void kt_transpose_cvt(const float* __restrict__ Wg,
                                                        u16* __restrict__ Wt){
  __shared__ u16 tile[64*66];
  int bx = blockIdx.x;            // 16 blocks: 4x4 tiles of 64x64
  int ti = bx >> 2, tj = bx & 3;
  int t = threadIdx.x;
#pragma unroll
  for (int i = 0; i < 16; ++i){
    int e = t*16 + i;
    int r = e >> 6, c = e & 63;
    tile[r*66 + c] = f2b(Wg[(ti*64 + r)*256 + tj*64 + c]);
  }
  __syncthreads();
#pragma unroll
  for (int i = 0; i < 16; ++i){
    int e = t*16 + i;
    int r = e >> 6, c = e & 63;   // r = g-local, c = f-local
    Wt[(tj*64 + r)*256 + ti*64 + c] = tile[c*66 + r];
  }
}

// ---- Kernel 1: P = x@W via MFMA, stored as P[bt][grp][s][j] bf16 (grp=g>>4),
//      plus q[r] = x[r]·W_l. grid 4096 = 2048 r-tiles x 2 g-tiles, 256 thr.
__global__ __launch_bounds__(256) void kt_gemm(const float* __restrict__ Xg,
                                               const u16* __restrict__ Wt,
                                               const float* __restrict__ Wlg,
                                               u16* __restrict__ Pg,
                                               float* __restrict__ qg){
  __shared__ u16 Ws[128*72];   // [g-local][k-local] pad 64->72
  __shared__ u16 Xs[128*72];   // [r-local][k-local]
  __shared__ float Wls[256];
  int t  = threadIdx.x;
  int bx = blockIdx.x;
  int mt = bx >> 1, nt = bx & 1;
  int r0 = mt*128, g0 = nt*128;
  Wls[t & 255] = Wlg[t & 255];
  int lane = t & 63, wv = t >> 6;
  int goff = (wv & 1)*64, roff = (wv >> 1)*64;
  int fr = lane & 15, fq = lane >> 4;
  f32x4 acc[4][4];
#pragma unroll
  for (int a = 0; a < 4; ++a)
#pragma unroll
    for (int b = 0; b < 4; ++b)
      acc[a][b] = (f32x4){0.f,0.f,0.f,0.f};
  float qacc = 0.f;

  for (int kk = 0; kk < 4; ++kk){
    int k0 = kk*64;
    __syncthreads();   // protect LDS reuse from previous iteration
#pragma unroll
    for (int uu = 0; uu < 4; ++uu){
      int unit = uu*256 + t;          // 0..1023
      int row = unit >> 3, c = unit & 7;
      // W tile: already bf16
      *(uint4*)&Ws[row*72 + c*8] = *(const uint4*)&Wt[(g0+row)*256 + k0 + c*8];
      // x tile: fp32 -> bf16 convert
      const float4* xp = (const float4*)&Xg[(size_t)(r0+row)*256 + k0 + c*8];
      *(uint4*)&Xs[row*72 + c*8] = pack8(xp[0], xp[1]);
    }
    __syncthreads();
    if (nt == 0 && t < 128){
      int r = t;
#pragma unroll
      for (int c = 0; c < 8; ++c){
        uint4 xv = *(const uint4*)&Xs[r*72 + c*8];
        const uint32_t* xw = (const uint32_t*)&xv;
#pragma unroll
        for (int p = 0; p < 4; ++p){
          qacc = fmaf(b2f_lo(xw[p]), Wls[k0 + c*8 + 2*p],     qacc);
          qacc = fmaf(b2f_hi(xw[p]), Wls[k0 + c*8 + 2*p + 1], qacc);
        }
      }
    }
#pragma unroll
    for (int ks = 0; ks < 64; ks += 32){
      bf16x8 af[4], bf_[4];
#pragma unroll
      for (int mi = 0; mi < 4; ++mi)
        af[mi] = *(const bf16x8*)&Ws[(goff + mi*16 + fr)*72 + ks + fq*8];
#pragma unroll
      for (int ni = 0; ni < 4; ++ni)
        bf_[ni] = *(const bf16x8*)&Xs[(roff + ni*16 + fr)*72 + ks + fq*8];
#pragma unroll
      for (int mi = 0; mi < 4; ++mi)
#pragma unroll
        for (int ni = 0; ni < 4; ++ni)
          acc[mi][ni] = __builtin_amdgcn_mfma_f32_16x16x32_bf16(
              af[mi], bf_[ni], acc[mi][ni], 0, 0, 0);
    }
  }
  // epilogue: D row m -> g = g0+goff+mi*16+fq*4+reg ; D col n -> r
#pragma unroll
  for (int mi = 0; mi < 4; ++mi){
    int g = g0 + goff + mi*16 + fq*4;
    int grp = g >> 4;                 // j0 = fq*4 = g & 15
#pragma unroll
    for (int ni = 0; ni < 4; ++ni){
      int r = r0 + roff + ni*16 + fr;
      int bt = r >> 6, s = r & 63;
      ushort4 st;
      st.x = f2b(acc[mi][ni][0]); st.y = f2b(acc[mi][ni][1]);
      st.z = f2b(acc[mi][ni][2]); st.w = f2b(acc[mi][ni][3]);
      *(ushort4*)&Pg[(size_t)bt*16384 + grp*1024 + s*16 + fq*4] = st;
    }
  }
  if (nt == 0 && t < 128) qg[r0 + t] = qacc;
}

// ---- Kernel 2 (v5): sequential scan, 3 barriers/step.
//  __launch_bounds__(1024,4): 1 block/CU -> 128-VGPR budget, no spills.
//  AB: gate (replicated per wave, from glc_p) ; GEMV c=ctx@Wc reduced via
//      shfl_xor and distributed IN-REGISTER via 16 shfls (A->B is intra-wave:
//      wave w produces c[16w..16w+16) and consumes exactly that f-slice);
//      fused tanh + ait partials -> pp.                       -> sync S1
//  C:  replicated softmax from pp; attended partials -> attp  -> sync S2
//  D:  reduce attp -> att; ctx update; outO/outC; glc_p       -> sync S3
__global__ __launch_bounds__(1024, 4) void kt_scan5(
    const float* __restrict__ Xg, const u16* __restrict__ Pf,
    const float* __restrict__ qf, const float* __restrict__ Wcg,
    const float* __restrict__ Wlcg, const float* __restrict__ blg,
    const float* __restrict__ biasg, const float* __restrict__ ug,
    float* __restrict__ out)
{
  __shared__ float ctx_s[256], bbr_s[256], ur_s[256], wlc_s[256];
  __shared__ float pp[64*17];        // ait partials [s][grp], stride 17
  __shared__ float attp[16*260];     // attended partials [wave][f]
  __shared__ float glc_p[4];

  const int tid   = threadIdx.x;
  const int b     = blockIdx.x;
  const int lane  = tid & 63;
  const int wave  = tid >> 6;          // 0..15
  const int g_loc = lane >> 2;         // GEMV: g-local 0..15
  const int fc    = lane & 3;          // GEMV: f-chunk (64 f each)
  const int gcol  = wave*16 + g_loc;   // GEMV output column
  const int f     = tid & 255;         // D-phase f-ownership

  // one-time: Wc slice in regs, bf16-packed, PRE-ROTATED by fc (bank-friendly)
  uint32_t wcp2[32];
#pragma unroll
  for (int i = 0; i < 16; ++i){
    int m  = (4*fc + i) & 15;
    int fb = fc*64 + m*4;
    wcp2[2*i]   = pack2(Wcg[(fb+0)*256 + gcol], Wcg[(fb+1)*256 + gcol]);
    wcp2[2*i+1] = pack2(Wcg[(fb+2)*256 + gcol], Wcg[(fb+3)*256 + gcol]);
  }

  if (tid < 256){
    ctx_s[tid] = 0.f;
    bbr_s[tid] = K2 * biasg[tid];
    ur_s[tid]  = ug[tid];
    wlc_s[tid] = Wlcg[tid];
  }
  if (tid < 4) glc_p[tid] = 0.f;
  const float blf = blg[0];
  float glcr = 0.f;                    // replicated in every wave

  // per-thread streaming pointers
  const u16*    pP = Pf + (size_t)(b*Tdim)*16384 + wave*1024 + lane*16;
  const float4* pX = (const float4*)Xg + (size_t)(b*Tdim)*4096 + wave*256 + lane;
  const float*  pq = qf + (size_t)(b*Tdim)*64 + lane;

  // preamble: P(0), q(0)
  uint32_t pw[8];
  {
    const uint4* pp_ = (const uint4*)pP;
    *(uint4*)&pw[0] = pp_[0]; *(uint4*)&pw[4] = pp_[1];
  }
  float qcur = pq[0];

  float* outO = out;
  float* outC = out + Bdim*Tdim*Fdim;
  float* outW = out + 2*Bdim*Tdim*Fdim;
  __syncthreads();

  for (int tt = 0; tt < Tdim; ++tt){
    const int bt    = b*Tdim + tt;
    const int nstep = (tt < Tdim-1) ? 1 : 0;

    // ---- prefetch issues: cover = the whole AB phase ----
    uint32_t pwn[8];                               // P(t+1): used in AB(t+1)
    {
      const uint4* pp_ = (const uint4*)(pP + (size_t)nstep*16384);
      *(uint4*)&pwn[0] = pp_[0]; *(uint4*)&pwn[4] = pp_[1];
    }
    float qn = pq[nstep*64];                       // q(t+1)
    float4 x0 = pX[0], x1 = pX[64], x2 = pX[128], x3 = pX[192];  // x(t): used in C(t)

    // ================= AB (fused) =================
    {
      // gate: replicated per wave, bit-identical in every wave
      glcr += glc_p[0] + glc_p[1] + glc_p[2] + glc_p[3];   // from D(t-1)
      float logit = glcr + blf + qcur;
      float sig = __builtin_amdgcn_rcpf(1.f + __builtin_exp2f(-LOG2E*logit));
      const float l2  = K2 * sig;
      const float l2b = K2 - K2*sig;

      // GEMV: c_g = sum_f ctx_f * Wc[f][g]; 4 lanes per g, 64 f each
      float pa = 0.f;
#pragma unroll
      for (int i = 0; i < 16; ++i){
        int m = (4*fc + i) & 15;               // rotated f-subblock
        float4 cv = *(const float4*)&ctx_s[fc*64 + m*4];
        pa = fmaf(cv.x, b2f_lo(wcp2[2*i]),   pa);
        pa = fmaf(cv.y, b2f_hi(wcp2[2*i]),   pa);
        pa = fmaf(cv.z, b2f_lo(wcp2[2*i+1]), pa);
        pa = fmaf(cv.w, b2f_hi(wcp2[2*i+1]), pa);
      }
      pa += __shfl_xor(pa, 1, 64);
      pa += __shfl_xor(pa, 2, 64);
      // distribute: c[j] = c_{16*wave + j}, held by lanes 4j..4j+3
      float c[16];
#pragma unroll
      for (int j = 0; j < 16; ++j)
        c[j] = __shfl(pa, 4*j, 64);

      // fused tanh + ait partial; thread (s=lane, grp=wave)
      float ait = 0.f;
#pragma unroll
      for (int j = 0; j < 16; ++j){
        float pv = (j & 1) ? b2f_hi(pw[j>>1]) : b2f_lo(pw[j>>1]);
        float bb = bbr_s[wave*16 + j];           // wave-uniform broadcast
        float uu = ur_s[wave*16 + j];
        float z  = fmaf(l2, pv, fmaf(l2b, c[j], bb));
        float e  = __builtin_exp2f(z);
        float r  = __builtin_amdgcn_rcpf(e + 1.f);
        ait += fmaf(-2.f*uu, r, uu);
      }
      pp[lane*17 + wave] = ait;
    }
    __syncthreads();                       // S1: pp visible

    // ================= C: softmax + attended =================
    {
      const int ppb = lane*17;
      float ait = 0.f;
#pragma unroll
      for (int k = 0; k < 16; ++k) ait += pp[ppb + k];
      float mx = ait;
#pragma unroll
      for (int off = 32; off > 0; off >>= 1)
        mx = fmaxf(mx, __shfl_xor(mx, off, 64));
      float e = __builtin_exp2f(LOG2E*(ait - mx));
      float ssum = e;
#pragma unroll
      for (int off = 32; off > 0; off >>= 1)
        ssum += __shfl_xor(ssum, off, 64);
      float denom = ssum + 1e-7f * __builtin_exp2f(-LOG2E*mx);
      float a = e * __builtin_amdgcn_rcpf(denom);
      if (wave == 0) outW[(size_t)bt*Sdim + lane] = a;

      // attended partials: this thread owns s in [4w,4w+4), f in [4l,4l+4)
      const float av0 = __shfl(a, wave*4 + 0, 64);
      const float av1 = __shfl(a, wave*4 + 1, 64);
      const float av2 = __shfl(a, wave*4 + 2, 64);
      const float av3 = __shfl(a, wave*4 + 3, 64);
      float4 acc;
      acc.x = av0*x0.x; acc.y = av0*x0.y; acc.z = av0*x0.z; acc.w = av0*x0.w;
      acc.x = fmaf(av1, x1.x, acc.x); acc.y = fmaf(av1, x1.y, acc.y);
      acc.z = fmaf(av1, x1.z, acc.z); acc.w = fmaf(av1, x1.w, acc.w);
      acc.x = fmaf(av2, x2.x, acc.x); acc.y = fmaf(av2, x2.y, acc.y);
      acc.z = fmaf(av2, x2.z, acc.z); acc.w = fmaf(av2, x2.w, acc.w);
      acc.x = fmaf(av3, x3.x, acc.x); acc.y = fmaf(av3, x3.y, acc.y);
      acc.z = fmaf(av3, x3.z, acc.z); acc.w = fmaf(av3, x3.w, acc.w);
      *(float4*)&attp[wave*260 + lane*4] = acc;
    }
    __syncthreads();                       // S2: attp visible

    // ================= D: reduce + ctx update + outputs =================
    if (tid < 256){
      float att = 0.f;
#pragma unroll
      for (int k = 0; k < 16; ++k) att += attp[k*260 + f];
      const size_t o = (size_t)bt*Fdim + f;
      outO[o] = att;
      float nc = ctx_s[f] + att;
      ctx_s[f] = nc;
      outC[o] = nc;
      float gp = att * wlc_s[f];
#pragma unroll
      for (int off = 32; off > 0; off >>= 1)
        gp += __shfl_xor(gp, off, 64);
      if (lane == 0) glc_p[wave] = gp;
    }
    __syncthreads();                       // S3: ctx_s/glc_p visible

    // rotate prefetched state
#pragma unroll
    for (int k = 0; k < 8; ++k) pw[k] = pwn[k];
    qcur = qn;
    pP += (size_t)nstep*16384;
    pX += 4096;
    pq += 64;
  }
}

// ===========================================================================
// FALLBACK (zero workspace) — the round-3 passing kernel, verbatim.
// ===========================================================================
__global__ __launch_bounds__(1024) void fused_ctx_attn(
    const float* __restrict__ Xg, const float* __restrict__ Wg,
    const float* __restrict__ Wcg, const float* __restrict__ Wlg,
    const float* __restrict__ Wlcg, const float* __restrict__ blg,
    const float* __restrict__ biasg, const float* __restrict__ ug,
    float* __restrict__ out)
{
  __shared__ u16   xs[64*272];
  __shared__ float ps[64*257];
  __shared__ float cpart[8*258];
  __shared__ float qp[64*5];
  __shared__ float pp[64*17];
  __shared__ float attp[4*260];
  __shared__ float ctx_s[256], c_s[256], bb_s[256], u_s[256], wlc_s[256], wl_s[256];
  __shared__ float l2_s[64], l2b_s[64], a_s[64];
  __shared__ float glc_p[4];

  const int tid  = threadIdx.x;
  const int b    = blockIdx.x;
  const int lane = tid & 63;
  const int wave = tid >> 6;
  const int fr   = lane & 15;
  const int fq   = lane >> 4;
  const int f    = tid & 255;
  const int sb   = tid >> 8;

  bf16x8 afW[8];
  {
    const int gcol = wave*16 + fr;
#pragma unroll
    for (int kt = 0; kt < 8; ++kt){
      u16 tmp[8];
#pragma unroll
      for (int j = 0; j < 8; ++j)
        tmp[j] = f2b(Wg[(kt*32 + fq*8 + j)*256 + gcol]);
      afW[kt] = *(const bf16x8*)tmp;
    }
  }
  const int fj = tid >> 7;
  const int gp = tid & 127;
  uint32_t wcp[32];
#pragma unroll
  for (int fi = 0; fi < 32; ++fi)
    wcp[fi] = pack2(Wcg[(fj*32 + fi)*256 + gp*2], Wcg[(fj*32 + fi)*256 + gp*2 + 1]);

  if (tid < 256){
    ctx_s[tid] = 0.f;
    bb_s[tid]  = K2 * biasg[tid];
    u_s[tid]   = ug[tid];
    wlc_s[tid] = Wlcg[tid];
    wl_s[tid]  = Wlg[tid];
  }
  if (tid < 4) glc_p[tid] = 0.f;
  const float blf = blg[0];
  float glcr = 0.f;

  float* outO = out;
  float* outC = out + Bdim*Tdim*Fdim;
  float* outW = out + 2*Bdim*Tdim*Fdim;

  const int srow = tid >> 5;
  const int sc8  = (tid & 31)*8;
  {
    const long xb = (long)(b*Tdim)*Sdim*Fdim;
    const float4* p0 = (const float4*)&Xg[xb + (long)srow*256 + sc8];
    const float4* p1 = (const float4*)&Xg[xb + (long)(srow+32)*256 + sc8];
    *(uint4*)&xs[srow*272 + sc8]      = pack8(p0[0], p0[1]);
    *(uint4*)&xs[(srow+32)*272 + sc8] = pack8(p1[0], p1[1]);
  }
  __syncthreads();

  for (int tt = 0; tt < Tdim; ++tt){
    const int tn = (tt < Tdim-1) ? (tt+1) : tt;
    const long xb = (long)((b*Tdim + tn))*Sdim*Fdim;
    const float4* p0 = (const float4*)&Xg[xb + (long)srow*256 + sc8];
    const float4* p1 = (const float4*)&Xg[xb + (long)(srow+32)*256 + sc8];
    uint4 xr0 = pack8(p0[0], p0[1]);
    uint4 xr1 = pack8(p1[0], p1[1]);

    {
      float pa = 0.f, pb = 0.f;
#pragma unroll
      for (int fi = 0; fi < 32; ++fi){
        float cf = ctx_s[fj*32 + fi];
        pa = fmaf(cf, b2f_lo(wcp[fi]), pa);
        pb = fmaf(cf, b2f_hi(wcp[fi]), pb);
      }
      float2 st; st.x = pa; st.y = pb;
      *(float2*)&cpart[fj*258 + gp*2] = st;
    }
    {
      f32x4 acc[4];
#pragma unroll
      for (int nt = 0; nt < 4; ++nt) acc[nt] = (f32x4){0.f,0.f,0.f,0.f};
#pragma unroll
      for (int kt = 0; kt < 8; ++kt){
#pragma unroll
        for (int nt = 0; nt < 4; ++nt){
          bf16x8 bfx = *(const bf16x8*)&xs[(nt*16 + fr)*272 + kt*32 + fq*8];
          acc[nt] = __builtin_amdgcn_mfma_f32_16x16x32_bf16(afW[kt], bfx, acc[nt], 0, 0, 0);
        }
      }
#pragma unroll
      for (int nt = 0; nt < 4; ++nt){
        const int s = nt*16 + fr;
        const int g = wave*16 + fq*4;
        ps[s*257 + g + 0] = acc[nt][0];
        ps[s*257 + g + 1] = acc[nt][1];
        ps[s*257 + g + 2] = acc[nt][2];
        ps[s*257 + g + 3] = acc[nt][3];
      }
    }
    if (tid < 256){
      const int s = tid >> 2, qtr = tid & 3;
      float a = 0.f;
#pragma unroll
      for (int j = 0; j < 64; ++j)
        a = fmaf(b2f(xs[s*272 + qtr*64 + j]), wl_s[qtr*64 + j], a);
      qp[s*5 + qtr] = a;
    }
    __syncthreads();

    if (tid < 256){
      float a = 0.f;
#pragma unroll
      for (int k = 0; k < 8; ++k) a += cpart[k*258 + tid];
      c_s[tid] = a;
    }
    if (tid < 64){
      glcr += glc_p[0] + glc_p[1] + glc_p[2] + glc_p[3];
      float q = qp[tid*5] + qp[tid*5+1] + qp[tid*5+2] + qp[tid*5+3];
      float logit = glcr + blf + q;
      float sig = 1.f / (1.f + __builtin_exp2f(-LOG2E*logit));
      l2_s[tid]  = K2 * sig;
      l2b_s[tid] = K2 - K2*sig;
    }
    __syncthreads();

    {
      const float cf = c_s[f], bbf = bb_s[f], uf = u_s[f], n2 = -2.f*u_s[f];
#pragma unroll
      for (int i = 0; i < 16; ++i){
        const int s = sb*16 + i;
        float z2 = fmaf(l2_s[s], ps[s*257 + f], fmaf(l2b_s[s], cf, bbf));
        float e  = __builtin_exp2f(z2);
        float r  = 1.f / (e + 1.f);
        ps[s*257 + f] = fmaf(n2, r, uf);
      }
    }
    __syncthreads();

    {
      const int s = tid & 63, grp = tid >> 6;
      float a = 0.f;
#pragma unroll
      for (int k = 0; k < 16; ++k) a += ps[s*257 + grp*16 + k];
      pp[s*17 + grp] = a;
    }
    __syncthreads();

    if (tid < 64){
      const int s = tid;
      float ait = 0.f;
#pragma unroll
      for (int k = 0; k < 16; ++k) ait += pp[s*17 + k];
      float m = ait;
#pragma unroll
      for (int off = 32; off > 0; off >>= 1)
        m = fmaxf(m, __shfl_xor(m, off, 64));
      float e = __builtin_exp2f(LOG2E*(ait - m));
      float ssum = e;
#pragma unroll
      for (int off = 32; off > 0; off >>= 1)
        ssum += __shfl_xor(ssum, off, 64);
      float denom = ssum + 1e-7f * __builtin_exp2f(-LOG2E*m);
      float a = e / denom;
      a_s[s] = a;
      outW[(b*Tdim + tt)*Sdim + s] = a;
    }
    __syncthreads();

    {
      float ap = 0.f;
#pragma unroll
      for (int i = 0; i < 16; ++i){
        const int s = sb*16 + i;
        ap = fmaf(a_s[s], b2f(xs[s*272 + f]), ap);
      }
      attp[sb*260 + f] = ap;
    }
    __syncthreads();

    if (tid < 256){
      float att = attp[f] + attp[260+f] + attp[520+f] + attp[780+f];
      const int o = (b*Tdim + tt)*Fdim + f;
      outO[o] = att;
      float nc = ctx_s[f] + att;
      ctx_s[f] = nc;
      outC[o] = nc;
      float gpart = att * wlc_s[f];
#pragma unroll
      for (int off = 32; off > 0; off >>= 1)
        gpart += __shfl_xor(gpart, off, 64);
      if (lane == 0) glc_p[wave] = gpart;
    }
    *(uint4*)&xs[srow*272 + sc8] = xr0;
    *(uint4*)&xs[(srow+32)*272 + sc8] = xr1;
    __syncthreads();
  }
}

// ---------------------------------------------------------------------------
extern "C" void kernel_launch(void* const* d_in, const int* in_sizes, int n_in,
                              void* d_out, int out_size, void* d_ws, size_t ws_size,
                              hipStream_t stream){
  const float* x    = (const float*)d_in[0];
  const float* W    = (const float*)d_in[1];
  const float* Wc   = (const float*)d_in[2];
  const float* Wl   = (const float*)d_in[3];
  const float* Wlc  = (const float*)d_in[4];
  const float* bl   = (const float*)d_in[5];
  const float* bias = (const float*)d_in[6];
  const float* u    = (const float*)d_in[7];
  float* out = (float*)d_out;

  const size_t P_BYTES  = (size_t)4096*16384*2;   // 134217728
  const size_t Q_BYTES  = (size_t)262144*4;       // 1048576
  const size_t WT_BYTES = (size_t)256*256*2;      // 131072
  const size_t NEED = P_BYTES + Q_BYTES + WT_BYTES;

  if (ws_size >= NEED){
    uint8_t* ws = (uint8_t*)d_ws;
    u16*   P  = (u16*)ws;
    float* q  = (float*)(ws + P_BYTES);
    u16*   Wt = (u16*)(ws + P_BYTES + Q_BYTES);
    kt_transpose_cvt<<<16, 256, 0, stream>>>(W, Wt);
    kt_gemm<<<4096, 256, 0, stream>>>(x, Wt, Wl, P, q);
    kt_scan5<<<Bdim, 1024, 0, stream>>>(x, P, q, Wc, Wlc, bl, bias, u, out);
  } else {
    fused_ctx_attn<<<Bdim, 1024, 0, stream>>>(x, W, Wc, Wl, Wlc, bl, bias, u, out);
  }
}